// Round 6
// baseline (400.860 us; speedup 1.0000x reference)
//
#include <hip/hip_runtime.h>
#include <math.h>

// ---------------------------------------------------------------------------
// SAGE pipeline, bf16-MFMA, round-11: agg47 clean edge-pair split + unroll16.
//   Round-10 post-mortem: 414->400 us (agg47 delta pair-split + Rz pack +
//   agg_dual128 unroll16 all landed). agg47 remains the slowest kernel and is
//   ISSUE-bound (VALU 50%, 2.2 TB/s): per 8 edges it still issues 8 clean
//   128-B row loads. This round pair-splits the CLEAN read too: lo half-wave
//   reads edge 2k's row (32 lanes x uint = 128 B, 2 cols/lane), hi half edge
//   2k+1 -> clean VMEM 8->4 per 8 edges (total VMEM 12->8), addressing
//   shared with delta (same 2*lq in-row offset), loop unrolled to 16 edges.
//   Clean sums recombined exactly like deltas: shfl_xor(32) + shfl(lane>>1).
//   Everything else unchanged from round-10 (best measured state):
//   P8 {128 fp8 clean | 128 fp8 delta} 256-B rows (delta re-based on rounded
//   clean), Rb bf16 self-term, Pzc bf16 + Pzd fp8 layer-2 tables, rank-based
//   CSR, merged prep/scan dispatches. NO nontemporal hints (round-8 lesson).
// ---------------------------------------------------------------------------

typedef unsigned int uint;
typedef unsigned short ushort;
typedef unsigned char uchar;
typedef short bf16x8 __attribute__((ext_vector_type(8)));
typedef float f32x4 __attribute__((ext_vector_type(4)));

__device__ __forceinline__ ushort f2b(float f) {  // fp32 -> bf16 RNE
  union { float f; uint u; } v; v.f = f;
  uint u = v.u;
  return (ushort)((u + 0x7FFFu + ((u >> 16) & 1u)) >> 16);
}
__device__ __forceinline__ float b2f_lo(uint u) {
  union { uint u; float f; } v; v.u = u << 16; return v.f;
}
__device__ __forceinline__ float b2f_hi(uint u) {
  union { uint u; float f; } v; v.u = u & 0xFFFF0000u; return v.f;
}

// ---- fp8 e4m3 helpers (hardware cvt on gfx950; guarded sw fallback) -------
#if __has_builtin(__builtin_amdgcn_cvt_f32_fp8)
__device__ __forceinline__ float dec8_0(uint u) { return __builtin_amdgcn_cvt_f32_fp8(u, 0); }
__device__ __forceinline__ float dec8_1(uint u) { return __builtin_amdgcn_cvt_f32_fp8(u, 1); }
__device__ __forceinline__ float dec8_2(uint u) { return __builtin_amdgcn_cvt_f32_fp8(u, 2); }
__device__ __forceinline__ float dec8_3(uint u) { return __builtin_amdgcn_cvt_f32_fp8(u, 3); }
#else
__device__ __forceinline__ float dec8_b(uint b) {
  uint s = (b >> 7) & 1u, ex = (b >> 3) & 0xFu, m = b & 7u;
  union { uint u; float f; } v;
  if (ex == 0) {
    v.f = (float)m * 0.001953125f;  // m * 2^-9
    v.u |= s << 31;
    return v.f;
  }
  v.u = (s << 31) | ((ex + 120u) << 23) | (m << 20);
  return v.f;
}
__device__ __forceinline__ float dec8_0(uint u) { return dec8_b(u & 0xFFu); }
__device__ __forceinline__ float dec8_1(uint u) { return dec8_b((u >> 8) & 0xFFu); }
__device__ __forceinline__ float dec8_2(uint u) { return dec8_b((u >> 16) & 0xFFu); }
__device__ __forceinline__ float dec8_3(uint u) { return dec8_b((u >> 24) & 0xFFu); }
#endif

#if __has_builtin(__builtin_amdgcn_cvt_pk_fp8_f32)
__device__ __forceinline__ uchar enc8(float f) {
  return (uchar)(__builtin_amdgcn_cvt_pk_fp8_f32(f, f, 0u, false) & 0xFFu);
}
#else
__device__ __forceinline__ uchar enc8(float f) {
  union { float f; uint u; } v; v.f = f;
  uint s = v.u >> 31;
  uint a = v.u & 0x7FFFFFFFu;
  if (a >= 0x43E00000u) return (uchar)((s << 7) | 0x7Eu);  // clamp +-448
  if (a < 0x3C800000u) {                                   // < 2^-6: subnormal
    float q = fabsf(f) * 512.0f;
    uint m = (uint)(q + 0.5f);
    return (uchar)((s << 7) | m);
  }
  uint r = a + 0x00080000u;
  if (r >= 0x43E00000u) return (uchar)((s << 7) | 0x7Eu);
  uint ex = (r >> 23) - 120u;
  uint m = (r >> 20) & 7u;
  return (uchar)((s << 7) | (ex << 3) | m);
}
#endif

// -------------------- prep: noisy+bf16 convert + weights + cnt=0 -----------
__global__ __launch_bounds__(256) void prep_kernel(
    const float* __restrict__ x, const float* __restrict__ noise,
    ushort* __restrict__ XB,
    const float* __restrict__ Wl0, const float* __restrict__ Wr0,
    const float* __restrict__ Wl1, const float* __restrict__ Wr1,
    const float* __restrict__ Wl2, const float* __restrict__ Wr2,
    ushort* __restrict__ WB0, ushort* __restrict__ WB1,
    ushort* __restrict__ WB2, int* __restrict__ cnt, int N) {
  int blk = blockIdx.x, t = threadIdx.x;
  if (blk < 64) {
    int i = blk * 256 + t;
    WB0[i] = f2b(Wl0[i]);
    WB0[16384 + i] = f2b(Wr0[i]);
    WB1[i] = f2b(Wl1[i]);
    WB1[16384 + i] = f2b(Wr1[i]);
    if (i < 6016) {
      WB2[i] = f2b(Wl2[i]);
      WB2[6016 + i] = f2b(Wr2[i]);
    }
  }
  {
    int i = blk * 256 + t;
    if (i < N) cnt[i] = 0;
  }
  int node = (blk * 256 + t) >> 6;
  int lane = t & 63;
  if (node >= N) return;
  size_t base = (size_t)node * 128 + 2 * lane;
  float2 nz = *(const float2*)(noise + base);
  float ss = nz.x * nz.x + nz.y * nz.y;
#pragma unroll
  for (int m = 1; m < 64; m <<= 1) ss += __shfl_xor(ss, m, 64);
  float scale = 0.1f / fmaxf(sqrtf(ss), 1e-12f);
  float2 xv = *(const float2*)(x + base);
  float s0 = (xv.x > 0.f) ? 1.f : ((xv.x < 0.f) ? -1.f : 0.f);
  float s1 = (xv.y > 0.f) ? 1.f : ((xv.y < 0.f) ? -1.f : 0.f);
  float n0 = xv.x + s0 * nz.x * scale;
  float n1 = xv.y + s1 * nz.y * scale;
  uint pc = ((uint)f2b(xv.y) << 16) | f2b(xv.x);
  uint pn = ((uint)f2b(n1) << 16) | f2b(n0);
  *(uint*)(XB + (size_t)(2 * node) * 128 + 2 * lane) = pc;
  *(uint*)(XB + (size_t)(2 * node + 1) * 128 + 2 * lane) = pn;
}

// ------------------------------- CSR build --------------------------------
__global__ __launch_bounds__(256) void count_kernel(
    const int* __restrict__ dst, int* __restrict__ cnt,
    int* __restrict__ rank, int E) {
  int e = blockIdx.x * blockDim.x + threadIdx.x;
  if (e >= E) return;
  rank[e] = atomicAdd(&cnt[dst[e]], 1);
}

__global__ __launch_bounds__(256) void scan_blocks(
    const int* __restrict__ cnt, int* __restrict__ loc,
    int* __restrict__ bsum, int n) {
  __shared__ int ls[4];
  int t = threadIdx.x;
  int base = blockIdx.x * 1024 + t * 4;
  int v[4];
  int s = 0;
#pragma unroll
  for (int i = 0; i < 4; ++i) {
    v[i] = (base + i < n) ? cnt[base + i] : 0;
    s += v[i];
  }
  int lane = t & 63, wid = t >> 6;
  int ps = s;
#pragma unroll
  for (int d = 1; d < 64; d <<= 1) {
    int o = __shfl_up(ps, d, 64);
    if (lane >= d) ps += o;
  }
  if (lane == 63) ls[wid] = ps;
  __syncthreads();
  if (t == 0) {
    int r = 0;
#pragma unroll
    for (int w = 0; w < 4; ++w) { int x = ls[w]; ls[w] = r; r += x; }
  }
  __syncthreads();
  int run = ps - s + ls[wid];
#pragma unroll
  for (int i = 0; i < 4; ++i) {
    if (base + i < n) loc[base + i] = run;
    run += v[i];
  }
  if (t == 255) bsum[blockIdx.x] = ps + ls[wid];
}

// merged: every block scans the (<=256) block sums redundantly in LDS, then
// applies. Removes the single-block scan_bsums kernel + its bubble.
__global__ __launch_bounds__(256) void scan_apply(
    const int* __restrict__ loc, const int* __restrict__ bsum,
    int* __restrict__ off, int n, int E, int nb) {
  __shared__ int ls[4];
  __shared__ int ex[256];
  int t = threadIdx.x;
  int v = (t < nb) ? bsum[t] : 0;
  int lane = t & 63, wid = t >> 6;
  int ps = v;
#pragma unroll
  for (int d = 1; d < 64; d <<= 1) {
    int o = __shfl_up(ps, d, 64);
    if (lane >= d) ps += o;
  }
  if (lane == 63) ls[wid] = ps;
  __syncthreads();
  if (t == 0) {
    int r = 0;
#pragma unroll
    for (int w = 0; w < 4; ++w) { int x = ls[w]; ls[w] = r; r += x; }
  }
  __syncthreads();
  ex[t] = ps - v + ls[wid];
  __syncthreads();
  int i = blockIdx.x * 256 + t;
  if (i < n) off[i] = loc[i] + ex[i >> 10];
  if (i == 0) off[n] = E;
}

__global__ __launch_bounds__(256) void fill_kernel(
    const int* __restrict__ src, const int* __restrict__ dst,
    const int* __restrict__ rank, const int* __restrict__ off,
    int* __restrict__ csr, int E) {
  int e = blockIdx.x * blockDim.x + threadIdx.x;
  if (e >= E) return;
  csr[off[dst[e]] + rank[e]] = src[e];
}

// ------------------------- GEMM layers 0/1 (fused) -------------------------
// A:[M][128] bf16 interleaved rows. W:[256][128] bf16 (Wl 0..127, Wr 128..255).
// 512 threads, 8 waves. cols 0..127 (Wl) -> P8: per node
// {128 fp8 clean | 128 fp8 delta} (256 B rows). cols 128..255 (Wr) -> Rb bf16
// [node][2][128].
__global__ __launch_bounds__(512) void gemm_fused(
    const ushort* __restrict__ A, const ushort* __restrict__ W,
    uchar* __restrict__ P8, ushort* __restrict__ Rb, int M) {
  __shared__ ushort As[128 * 72];   // stride 72 bf16 = 144 B (bank-safe)
  __shared__ ushort Ws[256 * 72];
  int tid = threadIdx.x;
  int lane = tid & 63, wid = tid >> 6;
  int wm = wid & 1, wn = wid >> 1;          // wn in 0..3
  int lrow = lane & 15, quad = lane >> 4;
  int row0 = blockIdx.x * 128;

  f32x4 acc[4][4];
#pragma unroll
  for (int mt = 0; mt < 4; ++mt)
#pragma unroll
    for (int nt = 0; nt < 4; ++nt) acc[mt][nt] = (f32x4)(0.f);

  for (int k0 = 0; k0 < 128; k0 += 64) {
    for (int c = tid; c < 128 * 8; c += 512) {
      int r = c >> 3, kc = c & 7;
      int gr = row0 + r;
      uint4 v = make_uint4(0, 0, 0, 0);
      if (gr < M) v = *(const uint4*)(A + (size_t)gr * 128 + k0 + kc * 8);
      *(uint4*)(As + r * 72 + kc * 8) = v;
    }
    for (int c = tid; c < 256 * 8; c += 512) {
      int r = c >> 3, kc = c & 7;
      uint4 v = *(const uint4*)(W + (size_t)r * 128 + k0 + kc * 8);
      *(uint4*)(Ws + r * 72 + kc * 8) = v;
    }
    __syncthreads();
#pragma unroll
    for (int ks = 0; ks < 64; ks += 32) {
      bf16x8 af[4], bw[4];
#pragma unroll
      for (int mt = 0; mt < 4; ++mt)
        af[mt] = *(const bf16x8*)(As + (wm * 64 + mt * 16 + lrow) * 72 + ks + quad * 8);
#pragma unroll
      for (int nt = 0; nt < 4; ++nt)
        bw[nt] = *(const bf16x8*)(Ws + (wn * 64 + nt * 16 + lrow) * 72 + ks + quad * 8);
#pragma unroll
      for (int mt = 0; mt < 4; ++mt)
#pragma unroll
        for (int nt = 0; nt < 4; ++nt)
          acc[mt][nt] = __builtin_amdgcn_mfma_f32_16x16x32_bf16(
              af[mt], bw[nt], acc[mt][nt], 0, 0, 0);
    }
    __syncthreads();
  }
  // epilogue. C/D layout: col = lane&15, row = quad*4 + rg. Interleaved rows
  // put a node's clean (even rg) and noisy (odd rg) in the SAME lane.
  if (wn < 2) {  // Wl -> P8 (fp8 clean + fp8 delta vs ROUNDED clean)
#pragma unroll
    for (int mt = 0; mt < 4; ++mt) {
#pragma unroll
      for (int nt = 0; nt < 4; ++nt) {
        int col = wn * 64 + nt * 16 + lrow;
#pragma unroll
        for (int rg = 0; rg < 4; rg += 2) {
          int row = row0 + wm * 64 + mt * 16 + quad * 4 + rg;  // even
          if (row >= M) continue;                              // M even
          int nd = row >> 1;
          float cv = acc[mt][nt][rg];
          float nv = acc[mt][nt][rg + 1];
          uchar c8 = enc8(cv);
          float cr = dec8_0((uint)c8);                 // rounded clean
          P8[(size_t)nd * 256 + col] = c8;
          P8[(size_t)nd * 256 + 128 + col] = enc8(nv - cr);
        }
      }
    }
  } else {  // Wr -> Rb bf16 [node][2][128]
#pragma unroll
    for (int mt = 0; mt < 4; ++mt) {
#pragma unroll
      for (int nt = 0; nt < 4; ++nt) {
        int colR = (wn - 2) * 64 + nt * 16 + lrow;
#pragma unroll
        for (int rg = 0; rg < 4; ++rg) {
          int row = row0 + wm * 64 + mt * 16 + quad * 4 + rg;
          if (row >= M) continue;
          int nd = row >> 1, hf = row & 1;
          Rb[(size_t)nd * 256 + hf * 128 + colR] = f2b(acc[mt][nt][rg]);
        }
      }
    }
  }
}

// ------------------------------ GEMM layer 2 -------------------------------
// 94 W rows (Wl2|Wr2). col<47 -> Pzc bf16 [node][64] + Pzd fp8 [node][64];
// col in [47,94) -> Rz f32 [node][96]: clean slots 0..46, noisy 48..94.
__global__ __launch_bounds__(256) void gemm_l2(
    const ushort* __restrict__ A, const ushort* __restrict__ W,
    ushort* __restrict__ Pzc, uchar* __restrict__ Pzd,
    float* __restrict__ Rz, int M) {
  constexpr int NT = 3;
  __shared__ ushort As[128 * 72];
  __shared__ ushort Ws[96 * 72];
  int tid = threadIdx.x;
  int lane = tid & 63, wid = tid >> 6;
  int wm = wid & 1, wn = wid >> 1;
  int lrow = lane & 15, quad = lane >> 4;
  int row0 = blockIdx.x * 128;

  f32x4 acc[4][NT];
#pragma unroll
  for (int mt = 0; mt < 4; ++mt)
#pragma unroll
    for (int nt = 0; nt < NT; ++nt) acc[mt][nt] = (f32x4)(0.f);

  for (int k0 = 0; k0 < 128; k0 += 64) {
    for (int c = tid; c < 128 * 8; c += 256) {
      int r = c >> 3, kc = c & 7;
      int gr = row0 + r;
      uint4 v = make_uint4(0, 0, 0, 0);
      if (gr < M) v = *(const uint4*)(A + (size_t)gr * 128 + k0 + kc * 8);
      *(uint4*)(As + r * 72 + kc * 8) = v;
    }
    for (int c = tid; c < 96 * 8; c += 256) {
      int r = c >> 3, kc = c & 7;
      uint4 v = make_uint4(0, 0, 0, 0);
      if (r < 94) v = *(const uint4*)(W + (size_t)r * 128 + k0 + kc * 8);
      *(uint4*)(Ws + r * 72 + kc * 8) = v;
    }
    __syncthreads();
#pragma unroll
    for (int ks = 0; ks < 64; ks += 32) {
      bf16x8 af[4], bw[NT];
#pragma unroll
      for (int mt = 0; mt < 4; ++mt)
        af[mt] = *(const bf16x8*)(As + (wm * 64 + mt * 16 + lrow) * 72 + ks + quad * 8);
#pragma unroll
      for (int nt = 0; nt < NT; ++nt)
        bw[nt] = *(const bf16x8*)(Ws + (wn * NT * 16 + nt * 16 + lrow) * 72 + ks + quad * 8);
#pragma unroll
      for (int mt = 0; mt < 4; ++mt)
#pragma unroll
        for (int nt = 0; nt < NT; ++nt)
          acc[mt][nt] = __builtin_amdgcn_mfma_f32_16x16x32_bf16(
              af[mt], bw[nt], acc[mt][nt], 0, 0, 0);
    }
    __syncthreads();
  }
#pragma unroll
  for (int mt = 0; mt < 4; ++mt) {
#pragma unroll
    for (int nt = 0; nt < NT; ++nt) {
      int col = wn * NT * 16 + nt * 16 + lrow;
#pragma unroll
      for (int rg = 0; rg < 4; rg += 2) {
        int row = row0 + wm * 64 + mt * 16 + quad * 4 + rg;  // even (clean)
        if (row >= M) continue;
        int nd = row >> 1;
        float cv = acc[mt][nt][rg];
        float nv = acc[mt][nt][rg + 1];
        if (col < 47) {
          ushort cb = f2b(cv);
          Pzc[(size_t)nd * 64 + col] = cb;
          Pzd[(size_t)nd * 64 + col] = enc8(nv - b2f_lo((uint)cb));
        } else if (col < 94) {
          Rz[(size_t)nd * 96 + (col - 47)] = cv;
          Rz[(size_t)nd * 96 + 48 + (col - 47)] = nv;
        }
      }
    }
  }
}

// ------------------------------ aggregation --------------------------------
// Layers 0/1: 1 wave per NODE. ONE uint per lane covers the full 256 B row:
// lanes 0-31 accumulate clean cols 4lq..4lq+3, lanes 32-63 the delta cols.
// Recombine with __shfl_xor(.,32): noisy_sum = clean_sum + delta_sum.
// Main loop unrolled x16 for gather queue depth.
template <bool WF32>
__global__ __launch_bounds__(256) void agg_dual128(
    const uchar* __restrict__ P8, const ushort* __restrict__ Rb,
    const float* __restrict__ bias, const int* __restrict__ off,
    const int* __restrict__ csr, float* __restrict__ f0,
    float* __restrict__ f1, ushort* __restrict__ bout, int N) {
  int node = (blockIdx.x * blockDim.x + threadIdx.x) >> 6;
  int lane = threadIdx.x & 63;
  if (node >= N) return;
  int lq = lane & 31;
  int b = off[node], e = off[node + 1];
  float s0 = 0.f, s1 = 0.f, s2 = 0.f, s3 = 0.f;
  float t0 = 0.f, t1 = 0.f, t2 = 0.f, t3 = 0.f;
  int j = b;
  for (; j + 16 <= e; j += 16) {
    int a0 = csr[j],      a1 = csr[j + 1],  a2 = csr[j + 2],  a3 = csr[j + 3];
    int a4 = csr[j + 4],  a5 = csr[j + 5],  a6 = csr[j + 6],  a7 = csr[j + 7];
    int a8 = csr[j + 8],  a9 = csr[j + 9],  aA = csr[j + 10], aB = csr[j + 11];
    int aC = csr[j + 12], aD = csr[j + 13], aE = csr[j + 14], aF = csr[j + 15];
    uint u0 = *(const uint*)(P8 + (size_t)a0 * 256 + 4 * lane);
    uint u1 = *(const uint*)(P8 + (size_t)a1 * 256 + 4 * lane);
    uint u2 = *(const uint*)(P8 + (size_t)a2 * 256 + 4 * lane);
    uint u3 = *(const uint*)(P8 + (size_t)a3 * 256 + 4 * lane);
    uint u4 = *(const uint*)(P8 + (size_t)a4 * 256 + 4 * lane);
    uint u5 = *(const uint*)(P8 + (size_t)a5 * 256 + 4 * lane);
    uint u6 = *(const uint*)(P8 + (size_t)a6 * 256 + 4 * lane);
    uint u7 = *(const uint*)(P8 + (size_t)a7 * 256 + 4 * lane);
    uint v0 = *(const uint*)(P8 + (size_t)a8 * 256 + 4 * lane);
    uint v1 = *(const uint*)(P8 + (size_t)a9 * 256 + 4 * lane);
    uint v2 = *(const uint*)(P8 + (size_t)aA * 256 + 4 * lane);
    uint v3 = *(const uint*)(P8 + (size_t)aB * 256 + 4 * lane);
    uint v4 = *(const uint*)(P8 + (size_t)aC * 256 + 4 * lane);
    uint v5 = *(const uint*)(P8 + (size_t)aD * 256 + 4 * lane);
    uint v6 = *(const uint*)(P8 + (size_t)aE * 256 + 4 * lane);
    uint v7 = *(const uint*)(P8 + (size_t)aF * 256 + 4 * lane);
    s0 += dec8_0(u0) + dec8_0(u1) + dec8_0(u2) + dec8_0(u3);
    s1 += dec8_1(u0) + dec8_1(u1) + dec8_1(u2) + dec8_1(u3);
    s2 += dec8_2(u0) + dec8_2(u1) + dec8_2(u2) + dec8_2(u3);
    s3 += dec8_3(u0) + dec8_3(u1) + dec8_3(u2) + dec8_3(u3);
    t0 += dec8_0(u4) + dec8_0(u5) + dec8_0(u6) + dec8_0(u7);
    t1 += dec8_1(u4) + dec8_1(u5) + dec8_1(u6) + dec8_1(u7);
    t2 += dec8_2(u4) + dec8_2(u5) + dec8_2(u6) + dec8_2(u7);
    t3 += dec8_3(u4) + dec8_3(u5) + dec8_3(u6) + dec8_3(u7);
    s0 += dec8_0(v0) + dec8_0(v1) + dec8_0(v2) + dec8_0(v3);
    s1 += dec8_1(v0) + dec8_1(v1) + dec8_1(v2) + dec8_1(v3);
    s2 += dec8_2(v0) + dec8_2(v1) + dec8_2(v2) + dec8_2(v3);
    s3 += dec8_3(v0) + dec8_3(v1) + dec8_3(v2) + dec8_3(v3);
    t0 += dec8_0(v4) + dec8_0(v5) + dec8_0(v6) + dec8_0(v7);
    t1 += dec8_1(v4) + dec8_1(v5) + dec8_1(v6) + dec8_1(v7);
    t2 += dec8_2(v4) + dec8_2(v5) + dec8_2(v6) + dec8_2(v7);
    t3 += dec8_3(v4) + dec8_3(v5) + dec8_3(v6) + dec8_3(v7);
  }
  if (j + 8 <= e) {
    int a0 = csr[j],     a1 = csr[j + 1], a2 = csr[j + 2], a3 = csr[j + 3];
    int a4 = csr[j + 4], a5 = csr[j + 5], a6 = csr[j + 6], a7 = csr[j + 7];
    uint u0 = *(const uint*)(P8 + (size_t)a0 * 256 + 4 * lane);
    uint u1 = *(const uint*)(P8 + (size_t)a1 * 256 + 4 * lane);
    uint u2 = *(const uint*)(P8 + (size_t)a2 * 256 + 4 * lane);
    uint u3 = *(const uint*)(P8 + (size_t)a3 * 256 + 4 * lane);
    uint u4 = *(const uint*)(P8 + (size_t)a4 * 256 + 4 * lane);
    uint u5 = *(const uint*)(P8 + (size_t)a5 * 256 + 4 * lane);
    uint u6 = *(const uint*)(P8 + (size_t)a6 * 256 + 4 * lane);
    uint u7 = *(const uint*)(P8 + (size_t)a7 * 256 + 4 * lane);
    s0 += dec8_0(u0) + dec8_0(u1) + dec8_0(u2) + dec8_0(u3);
    s1 += dec8_1(u0) + dec8_1(u1) + dec8_1(u2) + dec8_1(u3);
    s2 += dec8_2(u0) + dec8_2(u1) + dec8_2(u2) + dec8_2(u3);
    s3 += dec8_3(u0) + dec8_3(u1) + dec8_3(u2) + dec8_3(u3);
    t0 += dec8_0(u4) + dec8_0(u5) + dec8_0(u6) + dec8_0(u7);
    t1 += dec8_1(u4) + dec8_1(u5) + dec8_1(u6) + dec8_1(u7);
    t2 += dec8_2(u4) + dec8_2(u5) + dec8_2(u6) + dec8_2(u7);
    t3 += dec8_3(u4) + dec8_3(u5) + dec8_3(u6) + dec8_3(u7);
    j += 8;
  }
  if (j + 4 <= e) {
    int a0 = csr[j], a1 = csr[j + 1], a2 = csr[j + 2], a3 = csr[j + 3];
    uint u0 = *(const uint*)(P8 + (size_t)a0 * 256 + 4 * lane);
    uint u1 = *(const uint*)(P8 + (size_t)a1 * 256 + 4 * lane);
    uint u2 = *(const uint*)(P8 + (size_t)a2 * 256 + 4 * lane);
    uint u3 = *(const uint*)(P8 + (size_t)a3 * 256 + 4 * lane);
    s0 += dec8_0(u0) + dec8_0(u1) + dec8_0(u2) + dec8_0(u3);
    s1 += dec8_1(u0) + dec8_1(u1) + dec8_1(u2) + dec8_1(u3);
    s2 += dec8_2(u0) + dec8_2(u1) + dec8_2(u2) + dec8_2(u3);
    s3 += dec8_3(u0) + dec8_3(u1) + dec8_3(u2) + dec8_3(u3);
    j += 4;
  }
  for (; j < e; ++j) {
    uint u0 = *(const uint*)(P8 + (size_t)csr[j] * 256 + 4 * lane);
    s0 += dec8_0(u0);
    s1 += dec8_1(u0);
    s2 += dec8_2(u0);
    s3 += dec8_3(u0);
  }
  s0 += t0; s1 += t1; s2 += t2; s3 += t3;
  // cross-half exchange: low lanes get delta sums, high lanes get clean sums
  float o0 = __shfl_xor(s0, 32, 64);
  float o1 = __shfl_xor(s1, 32, 64);
  float o2 = __shfl_xor(s2, 32, 64);
  float o3 = __shfl_xor(s3, 32, 64);
  bool hi = lane >= 32;                       // hi half -> noisy branch
  float m0 = hi ? (s0 + o0) : s0;             // noisy = clean + delta
  float m1 = hi ? (s1 + o1) : s1;
  float m2 = hi ? (s2 + o2) : s2;
  float m3 = hi ? (s3 + o3) : s3;
  float invd = 1.f / (float)max(e - b, 1);
  // Rb row [2][128] bf16: element offset 4*lane spans clean(0-31)/noisy(32-63)
  uint2 rp = *(const uint2*)(Rb + (size_t)node * 256 + 4 * lane);
  float rvx = b2f_lo(rp.x), rvy = b2f_hi(rp.x);
  float rvz = b2f_lo(rp.y), rvw = b2f_hi(rp.y);
  float4 bb = *(const float4*)(bias + 4 * lq);
  float q0 = fmaxf(m0 * invd + bb.x + rvx, 0.f);
  float q1 = fmaxf(m1 * invd + bb.y + rvy, 0.f);
  float q2 = fmaxf(m2 * invd + bb.z + rvz, 0.f);
  float q3 = fmaxf(m3 * invd + bb.w + rvw, 0.f);
  size_t arow = (size_t)(2 * node + (hi ? 1 : 0)) * 128 + 4 * lq;
  ushort4 pk;
  pk.x = f2b(q0); pk.y = f2b(q1); pk.z = f2b(q2); pk.w = f2b(q3);
  *(ushort4*)(bout + arow) = pk;
  if (WF32) {
    float* dst = (hi ? f1 : f0) + (size_t)node * 128 + 4 * lq;
    *(float4*)dst = make_float4(q0, q1, q2, q3);
  }
}

// layer 2: FULLY pair-split gather. Per edge pair (2k, 2k+1): lo half-wave
// handles edge 2k, hi half edge 2k+1. Each lane reads the pair's clean row
// as uint (2 bf16 cols: 2lq, 2lq+1; 32 lanes x 4 B = full 128 B row) and the
// delta row as ushort (2 fp8 cols). Per 8 edges: 4 clean + 4 delta VMEM
// (was 8 + 4). Sums recombined via shfl_xor(32), redistributed col=lane via
// shfl(lane>>1). Fused log_softmax per branch over 47 lanes.
__global__ __launch_bounds__(256) void agg47_dual(
    const ushort* __restrict__ Pzc, const uchar* __restrict__ Pzd,
    const float* __restrict__ Rz, const float* __restrict__ bias,
    const int* __restrict__ off, const int* __restrict__ csr,
    float* __restrict__ z0, float* __restrict__ z1, float* __restrict__ y0,
    float* __restrict__ y1, int N) {
  int node = (blockIdx.x * blockDim.x + threadIdx.x) >> 6;
  int lane = threadIdx.x & 63;
  if (node >= N) return;
  int lq = lane & 31;
  bool hiH = lane >= 32;
  int b = off[node], e = off[node + 1];
  float c0s = 0.f, c1s = 0.f;   // clean partial sums, cols 2lq / 2lq+1
  float c2s = 0.f, c3s = 0.f;   // second accumulator pair (ILP)
  float g0 = 0.f, g1 = 0.f;     // delta partial sums, cols 2lq / 2lq+1
  float h0 = 0.f, h1 = 0.f;
  int j = b;
  for (; j + 16 <= e; j += 16) {
    int a0 = csr[j],      a1 = csr[j + 1],  a2 = csr[j + 2],  a3 = csr[j + 3];
    int a4 = csr[j + 4],  a5 = csr[j + 5],  a6 = csr[j + 6],  a7 = csr[j + 7];
    int a8 = csr[j + 8],  a9 = csr[j + 9],  aA = csr[j + 10], aB = csr[j + 11];
    int aC = csr[j + 12], aD = csr[j + 13], aE = csr[j + 14], aF = csr[j + 15];
    int p0 = hiH ? a1 : a0;   // pair split: lo half even edge, hi half odd
    int p1 = hiH ? a3 : a2;
    int p2 = hiH ? a5 : a4;
    int p3 = hiH ? a7 : a6;
    int p4 = hiH ? a9 : a8;
    int p5 = hiH ? aB : aA;
    int p6 = hiH ? aD : aC;
    int p7 = hiH ? aF : aE;
    uint c0 = *(const uint*)(Pzc + (size_t)p0 * 64 + 2 * lq);
    uint c1 = *(const uint*)(Pzc + (size_t)p1 * 64 + 2 * lq);
    uint c2 = *(const uint*)(Pzc + (size_t)p2 * 64 + 2 * lq);
    uint c3 = *(const uint*)(Pzc + (size_t)p3 * 64 + 2 * lq);
    uint c4 = *(const uint*)(Pzc + (size_t)p4 * 64 + 2 * lq);
    uint c5 = *(const uint*)(Pzc + (size_t)p5 * 64 + 2 * lq);
    uint c6 = *(const uint*)(Pzc + (size_t)p6 * 64 + 2 * lq);
    uint c7 = *(const uint*)(Pzc + (size_t)p7 * 64 + 2 * lq);
    uint d0 = *(const ushort*)(Pzd + (size_t)p0 * 64 + 2 * lq);
    uint d1 = *(const ushort*)(Pzd + (size_t)p1 * 64 + 2 * lq);
    uint d2 = *(const ushort*)(Pzd + (size_t)p2 * 64 + 2 * lq);
    uint d3 = *(const ushort*)(Pzd + (size_t)p3 * 64 + 2 * lq);
    uint d4 = *(const ushort*)(Pzd + (size_t)p4 * 64 + 2 * lq);
    uint d5 = *(const ushort*)(Pzd + (size_t)p5 * 64 + 2 * lq);
    uint d6 = *(const ushort*)(Pzd + (size_t)p6 * 64 + 2 * lq);
    uint d7 = *(const ushort*)(Pzd + (size_t)p7 * 64 + 2 * lq);
    c0s += b2f_lo(c0) + b2f_lo(c1) + b2f_lo(c2) + b2f_lo(c3);
    c1s += b2f_hi(c0) + b2f_hi(c1) + b2f_hi(c2) + b2f_hi(c3);
    c2s += b2f_lo(c4) + b2f_lo(c5) + b2f_lo(c6) + b2f_lo(c7);
    c3s += b2f_hi(c4) + b2f_hi(c5) + b2f_hi(c6) + b2f_hi(c7);
    g0 += dec8_0(d0) + dec8_0(d1) + dec8_0(d2) + dec8_0(d3);
    g1 += dec8_1(d0) + dec8_1(d1) + dec8_1(d2) + dec8_1(d3);
    h0 += dec8_0(d4) + dec8_0(d5) + dec8_0(d6) + dec8_0(d7);
    h1 += dec8_1(d4) + dec8_1(d5) + dec8_1(d6) + dec8_1(d7);
  }
  if (j + 8 <= e) {
    int a0 = csr[j],     a1 = csr[j + 1], a2 = csr[j + 2], a3 = csr[j + 3];
    int a4 = csr[j + 4], a5 = csr[j + 5], a6 = csr[j + 6], a7 = csr[j + 7];
    int p0 = hiH ? a1 : a0;
    int p1 = hiH ? a3 : a2;
    int p2 = hiH ? a5 : a4;
    int p3 = hiH ? a7 : a6;
    uint c0 = *(const uint*)(Pzc + (size_t)p0 * 64 + 2 * lq);
    uint c1 = *(const uint*)(Pzc + (size_t)p1 * 64 + 2 * lq);
    uint c2 = *(const uint*)(Pzc + (size_t)p2 * 64 + 2 * lq);
    uint c3 = *(const uint*)(Pzc + (size_t)p3 * 64 + 2 * lq);
    uint d0 = *(const ushort*)(Pzd + (size_t)p0 * 64 + 2 * lq);
    uint d1 = *(const ushort*)(Pzd + (size_t)p1 * 64 + 2 * lq);
    uint d2 = *(const ushort*)(Pzd + (size_t)p2 * 64 + 2 * lq);
    uint d3 = *(const ushort*)(Pzd + (size_t)p3 * 64 + 2 * lq);
    c0s += b2f_lo(c0) + b2f_lo(c1) + b2f_lo(c2) + b2f_lo(c3);
    c1s += b2f_hi(c0) + b2f_hi(c1) + b2f_hi(c2) + b2f_hi(c3);
    g0 += dec8_0(d0) + dec8_0(d1) + dec8_0(d2) + dec8_0(d3);
    g1 += dec8_1(d0) + dec8_1(d1) + dec8_1(d2) + dec8_1(d3);
    j += 8;
  }
  if (j + 4 <= e) {
    int a0 = csr[j], a1 = csr[j + 1], a2 = csr[j + 2], a3 = csr[j + 3];
    int p0 = hiH ? a1 : a0;
    int p1 = hiH ? a3 : a2;
    uint c0 = *(const uint*)(Pzc + (size_t)p0 * 64 + 2 * lq);
    uint c1 = *(const uint*)(Pzc + (size_t)p1 * 64 + 2 * lq);
    uint d0 = *(const ushort*)(Pzd + (size_t)p0 * 64 + 2 * lq);
    uint d1 = *(const ushort*)(Pzd + (size_t)p1 * 64 + 2 * lq);
    c0s += b2f_lo(c0) + b2f_lo(c1);
    c1s += b2f_hi(c0) + b2f_hi(c1);
    g0 += dec8_0(d0) + dec8_0(d1);
    g1 += dec8_1(d0) + dec8_1(d1);
    j += 2 * 2;
  }
  if (j + 2 <= e) {
    int a0 = csr[j], a1 = csr[j + 1];
    int p0 = hiH ? a1 : a0;
    uint c0 = *(const uint*)(Pzc + (size_t)p0 * 64 + 2 * lq);
    uint d0 = *(const ushort*)(Pzd + (size_t)p0 * 64 + 2 * lq);
    c0s += b2f_lo(c0);
    c1s += b2f_hi(c0);
    g0 += dec8_0(d0);
    g1 += dec8_1(d0);
    j += 2;
  }
  if (j < e) {          // lone edge: only lo half processes it
    int a0 = csr[j];
    if (!hiH) {
      uint c0 = *(const uint*)(Pzc + (size_t)a0 * 64 + 2 * lq);
      uint d0 = *(const ushort*)(Pzd + (size_t)a0 * 64 + 2 * lq);
      c0s += b2f_lo(c0);
      c1s += b2f_hi(c0);
      g0 += dec8_0(d0);
      g1 += dec8_1(d0);
    }
  }
  c0s += c2s; c1s += c3s; g0 += h0; g1 += h1;
  // combine the two halves' edge subsets -> totals on all lanes
  c0s += __shfl_xor(c0s, 32, 64);
  c1s += __shfl_xor(c1s, 32, 64);
  g0 += __shfl_xor(g0, 32, 64);
  g1 += __shfl_xor(g1, 32, 64);
  // value for col = lane lives on lane>>1 (component lane&1)
  float cc0 = __shfl(c0s, lane >> 1, 64);
  float cc1 = __shfl(c1s, lane >> 1, 64);
  float dd0 = __shfl(g0, lane >> 1, 64);
  float dd1 = __shfl(g1, lane >> 1, 64);
  float cl = (lane & 1) ? cc1 : cc0;
  float dl = (lane & 1) ? dd1 : dd0;
  bool v = lane < 47;
  float invd = 1.f / (float)max(e - b, 1);
  float rc = Rz[(size_t)node * 96 + lane];        // lanes 47..63: pad/garbage
  float rn = Rz[(size_t)node * 96 + 48 + lane];   // (masked by v below)
  float bl = v ? bias[lane] : 0.f;
  float za = v ? (cl * invd + bl + rc) : -INFINITY;
  float zn = v ? ((cl + dl) * invd + bl + rn) : -INFINITY;
  float ma = za, mb = zn;
#pragma unroll
  for (int d = 1; d < 64; d <<= 1) {
    ma = fmaxf(ma, __shfl_xor(ma, d, 64));
    mb = fmaxf(mb, __shfl_xor(mb, d, 64));
  }
  float sa = v ? __expf(za - ma) : 0.f;
  float sb = v ? __expf(zn - mb) : 0.f;
#pragma unroll
  for (int d = 1; d < 64; d <<= 1) {
    sa += __shfl_xor(sa, d, 64);
    sb += __shfl_xor(sb, d, 64);
  }
  float lsa = logf(sa) + ma;
  float lsb = logf(sb) + mb;
  if (v) {
    z0[(size_t)node * 47 + lane] = za;
    y0[(size_t)node * 47 + lane] = za - lsa;
    z1[(size_t)node * 47 + lane] = zn;
    y1[(size_t)node * 47 + lane] = zn - lsb;
  }
}

// ---------------------------------------------------------------------------
extern "C" void kernel_launch(void* const* d_in, const int* in_sizes, int n_in,
                              void* d_out, int out_size, void* d_ws,
                              size_t ws_size, hipStream_t stream) {
  const float* x = (const float*)d_in[0];
  const int* ei = (const int*)d_in[1];
  const float* noise = (const float*)d_in[2];
  const float* Wl0 = (const float*)d_in[3];
  const float* bl0 = (const float*)d_in[4];
  const float* Wr0 = (const float*)d_in[5];
  const float* Wl1 = (const float*)d_in[6];
  const float* bl1 = (const float*)d_in[7];
  const float* Wr1 = (const float*)d_in[8];
  const float* Wl2 = (const float*)d_in[9];
  const float* bl2 = (const float*)d_in[10];
  const float* Wr2 = (const float*)d_in[11];

  const int N = in_sizes[0] / 128;
  const int E = in_sizes[1] / 2;
  const int M = 2 * N;

  float* out = (float*)d_out;
  float* h_p = out;
  float* y_p = h_p + (size_t)N * 128;
  float* z_p = y_p + (size_t)N * 47;
  float* h_n = z_p + (size_t)N * 47;
  float* y_n = h_n + (size_t)N * 128;
  float* z_n = y_n + (size_t)N * 47;

  char* w = (char*)d_ws;
  auto alloc = [&](size_t bytes) {
    void* p = (void*)w;
    w += (bytes + 511) & ~(size_t)511;
    return p;
  };
  ushort* XB = (ushort*)alloc((size_t)M * 128 * 2);   // bf16 [M][128] interleaved
  uchar* P8 = (uchar*)alloc((size_t)N * 256);         // fp8 clean|delta rows
  ushort* Rb = (ushort*)alloc((size_t)M * 128 * 2);   // bf16 self-term L0/L1
  float* Rz = (float*)alloc((size_t)N * 128 * 4);     // f32 self-term L2 (96 used)
  ushort* WB0 = (ushort*)alloc(256 * 128 * 2);
  ushort* WB1 = (ushort*)alloc(256 * 128 * 2);
  ushort* WB2 = (ushort*)alloc(94 * 128 * 2);
  int* cnt = (int*)alloc((size_t)N * 4);
  int* off = (int*)alloc((size_t)(N + 1) * 4);
  int* rank = (int*)alloc((size_t)E * 4);
  int* loc = (int*)alloc((size_t)N * 4);
  int* bsum = (int*)alloc((size_t)256 * 4);
  int* csr = (int*)alloc((size_t)E * 4);
  // layer-2 tables carved from P8 region (N*128 B + N*64 B <= N*256 B)
  ushort* Pzc = (ushort*)P8;
  uchar* Pzd = P8 + (size_t)N * 128;

  int nwb = (N + 3) / 4;       // 1 wave/node
  int rb = (M + 127) / 128;    // GEMM row blocks
  int eb = (E + 255) / 256;
  int sb = (N + 1023) / 1024;

  // prep: noisy+bf16 convert, weight convert, cnt zero (one dispatch)
  prep_kernel<<<nwb, 256, 0, stream>>>(x, noise, XB, Wl0, Wr0, Wl1, Wr1, Wl2,
                                       Wr2, WB0, WB1, WB2, cnt, N);

  // CSR build (rank-based: fill has no atomics; scan_bsums merged into apply)
  count_kernel<<<eb, 256, 0, stream>>>(ei + E, cnt, rank, E);
  scan_blocks<<<sb, 256, 0, stream>>>(cnt, loc, bsum, N);
  scan_apply<<<(N + 255) / 256, 256, 0, stream>>>(loc, bsum, off, N, E, sb);
  fill_kernel<<<eb, 256, 0, stream>>>(ei, ei + E, rank, off, csr, E);

  // layer 0
  gemm_fused<<<rb, 512, 0, stream>>>(XB, WB0, P8, Rb, M);
  agg_dual128<false><<<nwb, 256, 0, stream>>>(P8, Rb, bl0, off, csr, nullptr,
                                              nullptr, XB, N);
  // layer 1 (h outputs + bf16 for next layer)
  gemm_fused<<<rb, 512, 0, stream>>>(XB, WB1, P8, Rb, M);
  agg_dual128<true><<<nwb, 256, 0, stream>>>(P8, Rb, bl1, off, csr, h_p, h_n,
                                             XB, N);
  // layer 2 + fused log_softmax
  gemm_l2<<<rb, 256, 0, stream>>>(XB, WB2, Pzc, Pzd, Rz, M);
  agg47_dual<<<nwb, 256, 0, stream>>>(Pzc, Pzd, Rz, bl2, off, csr, z_p, z_n,
                                      y_p, y_n, N);
}

// Round 7
// 384.914 us; speedup vs baseline: 1.0414x; 1.0414x over previous
//
#include <hip/hip_runtime.h>
#include <math.h>

// ---------------------------------------------------------------------------
// SAGE pipeline, bf16-MFMA, round-12: hide CSR build under prep/gemm0.
//   Round-11 post-mortem: agg47 clean pair-split NEUTRAL (399.7->400.9) -
//   gather kernels are bound by random-access LINE throughput (lines/edge
//   unchanged by the split), not VMEM instruction issue. Instruction-count
//   tricks are dead; bytes/lines per edge is the only gather lever, and all
//   tables sit at their compulsory floor.
//   This round attacks the serial pipeline overhead instead (no numerics
//   changes): count (~13 us, E atomics) and fill (~18 us, E scatter) have no
//   data dependence on prep / gemm0 but sat as standalone dispatches on the
//   critical path. Graph capture forbids event forking, so fuse them:
//   - cnt zero -> hipMemsetAsync; count merged into prep (blocks < eb also
//     process 256 edges each).
//   - fill merged into layer-0 gemm_fused (grid = rb + 782 scatter blocks;
//     per-block-uniform role branch keeps __syncthreads legal).
//   10 dispatches + memset -> 8 + memset; ~30 us of work hidden.
//   Everything else identical to round-11 (best measured structure).
// ---------------------------------------------------------------------------

typedef unsigned int uint;
typedef unsigned short ushort;
typedef unsigned char uchar;
typedef short bf16x8 __attribute__((ext_vector_type(8)));
typedef float f32x4 __attribute__((ext_vector_type(4)));

__device__ __forceinline__ ushort f2b(float f) {  // fp32 -> bf16 RNE
  union { float f; uint u; } v; v.f = f;
  uint u = v.u;
  return (ushort)((u + 0x7FFFu + ((u >> 16) & 1u)) >> 16);
}
__device__ __forceinline__ float b2f_lo(uint u) {
  union { uint u; float f; } v; v.u = u << 16; return v.f;
}
__device__ __forceinline__ float b2f_hi(uint u) {
  union { uint u; float f; } v; v.u = u & 0xFFFF0000u; return v.f;
}

// ---- fp8 e4m3 helpers (hardware cvt on gfx950; guarded sw fallback) -------
#if __has_builtin(__builtin_amdgcn_cvt_f32_fp8)
__device__ __forceinline__ float dec8_0(uint u) { return __builtin_amdgcn_cvt_f32_fp8(u, 0); }
__device__ __forceinline__ float dec8_1(uint u) { return __builtin_amdgcn_cvt_f32_fp8(u, 1); }
__device__ __forceinline__ float dec8_2(uint u) { return __builtin_amdgcn_cvt_f32_fp8(u, 2); }
__device__ __forceinline__ float dec8_3(uint u) { return __builtin_amdgcn_cvt_f32_fp8(u, 3); }
#else
__device__ __forceinline__ float dec8_b(uint b) {
  uint s = (b >> 7) & 1u, ex = (b >> 3) & 0xFu, m = b & 7u;
  union { uint u; float f; } v;
  if (ex == 0) {
    v.f = (float)m * 0.001953125f;  // m * 2^-9
    v.u |= s << 31;
    return v.f;
  }
  v.u = (s << 31) | ((ex + 120u) << 23) | (m << 20);
  return v.f;
}
__device__ __forceinline__ float dec8_0(uint u) { return dec8_b(u & 0xFFu); }
__device__ __forceinline__ float dec8_1(uint u) { return dec8_b((u >> 8) & 0xFFu); }
__device__ __forceinline__ float dec8_2(uint u) { return dec8_b((u >> 16) & 0xFFu); }
__device__ __forceinline__ float dec8_3(uint u) { return dec8_b((u >> 24) & 0xFFu); }
#endif

#if __has_builtin(__builtin_amdgcn_cvt_pk_fp8_f32)
__device__ __forceinline__ uchar enc8(float f) {
  return (uchar)(__builtin_amdgcn_cvt_pk_fp8_f32(f, f, 0u, false) & 0xFFu);
}
#else
__device__ __forceinline__ uchar enc8(float f) {
  union { float f; uint u; } v; v.f = f;
  uint s = v.u >> 31;
  uint a = v.u & 0x7FFFFFFFu;
  if (a >= 0x43E00000u) return (uchar)((s << 7) | 0x7Eu);  // clamp +-448
  if (a < 0x3C800000u) {                                   // < 2^-6: subnormal
    float q = fabsf(f) * 512.0f;
    uint m = (uint)(q + 0.5f);
    return (uchar)((s << 7) | m);
  }
  uint r = a + 0x00080000u;
  if (r >= 0x43E00000u) return (uchar)((s << 7) | 0x7Eu);
  uint ex = (r >> 23) - 120u;
  uint m = (r >> 20) & 7u;
  return (uchar)((s << 7) | (ex << 3) | m);
}
#endif

// ----- prep: noisy+bf16 convert + weights + CSR count (cnt pre-zeroed) -----
// Block roles overlap: blk<64 -> weight convert; blk<eb -> 256 edges of the
// count pass (rank = per-dst arrival order); all blocks -> node conversion.
__global__ __launch_bounds__(256) void prep_kernel(
    const float* __restrict__ x, const float* __restrict__ noise,
    ushort* __restrict__ XB,
    const float* __restrict__ Wl0, const float* __restrict__ Wr0,
    const float* __restrict__ Wl1, const float* __restrict__ Wr1,
    const float* __restrict__ Wl2, const float* __restrict__ Wr2,
    ushort* __restrict__ WB0, ushort* __restrict__ WB1,
    ushort* __restrict__ WB2, const int* __restrict__ dst,
    int* __restrict__ cnt, int* __restrict__ rank, int E, int eb, int N) {
  int blk = blockIdx.x, t = threadIdx.x;
  if (blk < 64) {
    int i = blk * 256 + t;
    WB0[i] = f2b(Wl0[i]);
    WB0[16384 + i] = f2b(Wr0[i]);
    WB1[i] = f2b(Wl1[i]);
    WB1[16384 + i] = f2b(Wr1[i]);
    if (i < 6016) {
      WB2[i] = f2b(Wl2[i]);
      WB2[6016 + i] = f2b(Wr2[i]);
    }
  }
  if (blk < eb) {
    int e = blk * 256 + t;
    if (e < E) rank[e] = atomicAdd(&cnt[dst[e]], 1);
  }
  int node = (blk * 256 + t) >> 6;
  int lane = t & 63;
  if (node >= N) return;
  size_t base = (size_t)node * 128 + 2 * lane;
  float2 nz = *(const float2*)(noise + base);
  float ss = nz.x * nz.x + nz.y * nz.y;
#pragma unroll
  for (int m = 1; m < 64; m <<= 1) ss += __shfl_xor(ss, m, 64);
  float scale = 0.1f / fmaxf(sqrtf(ss), 1e-12f);
  float2 xv = *(const float2*)(x + base);
  float s0 = (xv.x > 0.f) ? 1.f : ((xv.x < 0.f) ? -1.f : 0.f);
  float s1 = (xv.y > 0.f) ? 1.f : ((xv.y < 0.f) ? -1.f : 0.f);
  float n0 = xv.x + s0 * nz.x * scale;
  float n1 = xv.y + s1 * nz.y * scale;
  uint pc = ((uint)f2b(xv.y) << 16) | f2b(xv.x);
  uint pn = ((uint)f2b(n1) << 16) | f2b(n0);
  *(uint*)(XB + (size_t)(2 * node) * 128 + 2 * lane) = pc;
  *(uint*)(XB + (size_t)(2 * node + 1) * 128 + 2 * lane) = pn;
}

// ------------------------------- CSR scans --------------------------------
__global__ __launch_bounds__(256) void scan_blocks(
    const int* __restrict__ cnt, int* __restrict__ loc,
    int* __restrict__ bsum, int n) {
  __shared__ int ls[4];
  int t = threadIdx.x;
  int base = blockIdx.x * 1024 + t * 4;
  int v[4];
  int s = 0;
#pragma unroll
  for (int i = 0; i < 4; ++i) {
    v[i] = (base + i < n) ? cnt[base + i] : 0;
    s += v[i];
  }
  int lane = t & 63, wid = t >> 6;
  int ps = s;
#pragma unroll
  for (int d = 1; d < 64; d <<= 1) {
    int o = __shfl_up(ps, d, 64);
    if (lane >= d) ps += o;
  }
  if (lane == 63) ls[wid] = ps;
  __syncthreads();
  if (t == 0) {
    int r = 0;
#pragma unroll
    for (int w = 0; w < 4; ++w) { int x = ls[w]; ls[w] = r; r += x; }
  }
  __syncthreads();
  int run = ps - s + ls[wid];
#pragma unroll
  for (int i = 0; i < 4; ++i) {
    if (base + i < n) loc[base + i] = run;
    run += v[i];
  }
  if (t == 255) bsum[blockIdx.x] = ps + ls[wid];
}

// merged: every block scans the (<=256) block sums redundantly in LDS, then
// applies. No single-block bubble.
__global__ __launch_bounds__(256) void scan_apply(
    const int* __restrict__ loc, const int* __restrict__ bsum,
    int* __restrict__ off, int n, int E, int nb) {
  __shared__ int ls[4];
  __shared__ int ex[256];
  int t = threadIdx.x;
  int v = (t < nb) ? bsum[t] : 0;
  int lane = t & 63, wid = t >> 6;
  int ps = v;
#pragma unroll
  for (int d = 1; d < 64; d <<= 1) {
    int o = __shfl_up(ps, d, 64);
    if (lane >= d) ps += o;
  }
  if (lane == 63) ls[wid] = ps;
  __syncthreads();
  if (t == 0) {
    int r = 0;
#pragma unroll
    for (int w = 0; w < 4; ++w) { int x = ls[w]; ls[w] = r; r += x; }
  }
  __syncthreads();
  ex[t] = ps - v + ls[wid];
  __syncthreads();
  int i = blockIdx.x * 256 + t;
  if (i < n) off[i] = loc[i] + ex[i >> 10];
  if (i == 0) off[n] = E;
}

// ------------------------- GEMM layers 0/1 (fused) -------------------------
// A:[M][128] bf16 interleaved rows. W:[256][128] bf16 (Wl 0..127, Wr 128..255).
// 512 threads, 8 waves. cols 0..127 (Wl) -> P8: per node
// {128 fp8 clean | 128 fp8 delta} (256 B rows). cols 128..255 (Wr) -> Rb bf16
// [node][2][128].
// Blocks >= rb (layer 0 only): CSR fill scatter (2 edges/thread) - uniform
// per-block role branch, runs concurrently with the GEMM blocks.
__global__ __launch_bounds__(512) void gemm_fused(
    const ushort* __restrict__ A, const ushort* __restrict__ W,
    uchar* __restrict__ P8, ushort* __restrict__ Rb, int M,
    const int* __restrict__ src, const int* __restrict__ dst,
    const int* __restrict__ rank, const int* __restrict__ off,
    int* __restrict__ csr, int E, int rb) {
  __shared__ ushort As[128 * 72];   // stride 72 bf16 = 144 B (bank-safe)
  __shared__ ushort Ws[256 * 72];
  int tid = threadIdx.x;
  if (blockIdx.x >= rb) {           // fill role (layer-0 dispatch only)
    int base = (blockIdx.x - rb) * 1024 + tid;
    if (base < E) csr[off[dst[base]] + rank[base]] = src[base];
    int e1 = base + 512;
    if (e1 < E) csr[off[dst[e1]] + rank[e1]] = src[e1];
    return;
  }
  int lane = tid & 63, wid = tid >> 6;
  int wm = wid & 1, wn = wid >> 1;          // wn in 0..3
  int lrow = lane & 15, quad = lane >> 4;
  int row0 = blockIdx.x * 128;

  f32x4 acc[4][4];
#pragma unroll
  for (int mt = 0; mt < 4; ++mt)
#pragma unroll
    for (int nt = 0; nt < 4; ++nt) acc[mt][nt] = (f32x4)(0.f);

  for (int k0 = 0; k0 < 128; k0 += 64) {
    for (int c = tid; c < 128 * 8; c += 512) {
      int r = c >> 3, kc = c & 7;
      int gr = row0 + r;
      uint4 v = make_uint4(0, 0, 0, 0);
      if (gr < M) v = *(const uint4*)(A + (size_t)gr * 128 + k0 + kc * 8);
      *(uint4*)(As + r * 72 + kc * 8) = v;
    }
    for (int c = tid; c < 256 * 8; c += 512) {
      int r = c >> 3, kc = c & 7;
      uint4 v = *(const uint4*)(W + (size_t)r * 128 + k0 + kc * 8);
      *(uint4*)(Ws + r * 72 + kc * 8) = v;
    }
    __syncthreads();
#pragma unroll
    for (int ks = 0; ks < 64; ks += 32) {
      bf16x8 af[4], bw[4];
#pragma unroll
      for (int mt = 0; mt < 4; ++mt)
        af[mt] = *(const bf16x8*)(As + (wm * 64 + mt * 16 + lrow) * 72 + ks + quad * 8);
#pragma unroll
      for (int nt = 0; nt < 4; ++nt)
        bw[nt] = *(const bf16x8*)(Ws + (wn * 64 + nt * 16 + lrow) * 72 + ks + quad * 8);
#pragma unroll
      for (int mt = 0; mt < 4; ++mt)
#pragma unroll
        for (int nt = 0; nt < 4; ++nt)
          acc[mt][nt] = __builtin_amdgcn_mfma_f32_16x16x32_bf16(
              af[mt], bw[nt], acc[mt][nt], 0, 0, 0);
    }
    __syncthreads();
  }
  // epilogue. C/D layout: col = lane&15, row = quad*4 + rg. Interleaved rows
  // put a node's clean (even rg) and noisy (odd rg) in the SAME lane.
  if (wn < 2) {  // Wl -> P8 (fp8 clean + fp8 delta vs ROUNDED clean)
#pragma unroll
    for (int mt = 0; mt < 4; ++mt) {
#pragma unroll
      for (int nt = 0; nt < 4; ++nt) {
        int col = wn * 64 + nt * 16 + lrow;
#pragma unroll
        for (int rg = 0; rg < 4; rg += 2) {
          int row = row0 + wm * 64 + mt * 16 + quad * 4 + rg;  // even
          if (row >= M) continue;                              // M even
          int nd = row >> 1;
          float cv = acc[mt][nt][rg];
          float nv = acc[mt][nt][rg + 1];
          uchar c8 = enc8(cv);
          float cr = dec8_0((uint)c8);                 // rounded clean
          P8[(size_t)nd * 256 + col] = c8;
          P8[(size_t)nd * 256 + 128 + col] = enc8(nv - cr);
        }
      }
    }
  } else {  // Wr -> Rb bf16 [node][2][128]
#pragma unroll
    for (int mt = 0; mt < 4; ++mt) {
#pragma unroll
      for (int nt = 0; nt < 4; ++nt) {
        int colR = (wn - 2) * 64 + nt * 16 + lrow;
#pragma unroll
        for (int rg = 0; rg < 4; ++rg) {
          int row = row0 + wm * 64 + mt * 16 + quad * 4 + rg;
          if (row >= M) continue;
          int nd = row >> 1, hf = row & 1;
          Rb[(size_t)nd * 256 + hf * 128 + colR] = f2b(acc[mt][nt][rg]);
        }
      }
    }
  }
}

// ------------------------------ GEMM layer 2 -------------------------------
// 94 W rows (Wl2|Wr2). col<47 -> Pzc bf16 [node][64] + Pzd fp8 [node][64];
// col in [47,94) -> Rz f32 [node][96]: clean slots 0..46, noisy 48..94.
__global__ __launch_bounds__(256) void gemm_l2(
    const ushort* __restrict__ A, const ushort* __restrict__ W,
    ushort* __restrict__ Pzc, uchar* __restrict__ Pzd,
    float* __restrict__ Rz, int M) {
  constexpr int NT = 3;
  __shared__ ushort As[128 * 72];
  __shared__ ushort Ws[96 * 72];
  int tid = threadIdx.x;
  int lane = tid & 63, wid = tid >> 6;
  int wm = wid & 1, wn = wid >> 1;
  int lrow = lane & 15, quad = lane >> 4;
  int row0 = blockIdx.x * 128;

  f32x4 acc[4][NT];
#pragma unroll
  for (int mt = 0; mt < 4; ++mt)
#pragma unroll
    for (int nt = 0; nt < NT; ++nt) acc[mt][nt] = (f32x4)(0.f);

  for (int k0 = 0; k0 < 128; k0 += 64) {
    for (int c = tid; c < 128 * 8; c += 256) {
      int r = c >> 3, kc = c & 7;
      int gr = row0 + r;
      uint4 v = make_uint4(0, 0, 0, 0);
      if (gr < M) v = *(const uint4*)(A + (size_t)gr * 128 + k0 + kc * 8);
      *(uint4*)(As + r * 72 + kc * 8) = v;
    }
    for (int c = tid; c < 96 * 8; c += 256) {
      int r = c >> 3, kc = c & 7;
      uint4 v = make_uint4(0, 0, 0, 0);
      if (r < 94) v = *(const uint4*)(W + (size_t)r * 128 + k0 + kc * 8);
      *(uint4*)(Ws + r * 72 + kc * 8) = v;
    }
    __syncthreads();
#pragma unroll
    for (int ks = 0; ks < 64; ks += 32) {
      bf16x8 af[4], bw[NT];
#pragma unroll
      for (int mt = 0; mt < 4; ++mt)
        af[mt] = *(const bf16x8*)(As + (wm * 64 + mt * 16 + lrow) * 72 + ks + quad * 8);
#pragma unroll
      for (int nt = 0; nt < NT; ++nt)
        bw[nt] = *(const bf16x8*)(Ws + (wn * NT * 16 + nt * 16 + lrow) * 72 + ks + quad * 8);
#pragma unroll
      for (int mt = 0; mt < 4; ++mt)
#pragma unroll
        for (int nt = 0; nt < NT; ++nt)
          acc[mt][nt] = __builtin_amdgcn_mfma_f32_16x16x32_bf16(
              af[mt], bw[nt], acc[mt][nt], 0, 0, 0);
    }
    __syncthreads();
  }
#pragma unroll
  for (int mt = 0; mt < 4; ++mt) {
#pragma unroll
    for (int nt = 0; nt < NT; ++nt) {
      int col = wn * NT * 16 + nt * 16 + lrow;
#pragma unroll
      for (int rg = 0; rg < 4; rg += 2) {
        int row = row0 + wm * 64 + mt * 16 + quad * 4 + rg;  // even (clean)
        if (row >= M) continue;
        int nd = row >> 1;
        float cv = acc[mt][nt][rg];
        float nv = acc[mt][nt][rg + 1];
        if (col < 47) {
          ushort cb = f2b(cv);
          Pzc[(size_t)nd * 64 + col] = cb;
          Pzd[(size_t)nd * 64 + col] = enc8(nv - b2f_lo((uint)cb));
        } else if (col < 94) {
          Rz[(size_t)nd * 96 + (col - 47)] = cv;
          Rz[(size_t)nd * 96 + 48 + (col - 47)] = nv;
        }
      }
    }
  }
}

// ------------------------------ aggregation --------------------------------
// Layers 0/1: 1 wave per NODE. ONE uint per lane covers the full 256 B row:
// lanes 0-31 accumulate clean cols 4lq..4lq+3, lanes 32-63 the delta cols.
// Recombine with __shfl_xor(.,32): noisy_sum = clean_sum + delta_sum.
// Main loop unrolled x16 for gather queue depth.
template <bool WF32>
__global__ __launch_bounds__(256) void agg_dual128(
    const uchar* __restrict__ P8, const ushort* __restrict__ Rb,
    const float* __restrict__ bias, const int* __restrict__ off,
    const int* __restrict__ csr, float* __restrict__ f0,
    float* __restrict__ f1, ushort* __restrict__ bout, int N) {
  int node = (blockIdx.x * blockDim.x + threadIdx.x) >> 6;
  int lane = threadIdx.x & 63;
  if (node >= N) return;
  int lq = lane & 31;
  int b = off[node], e = off[node + 1];
  float s0 = 0.f, s1 = 0.f, s2 = 0.f, s3 = 0.f;
  float t0 = 0.f, t1 = 0.f, t2 = 0.f, t3 = 0.f;
  int j = b;
  for (; j + 16 <= e; j += 16) {
    int a0 = csr[j],      a1 = csr[j + 1],  a2 = csr[j + 2],  a3 = csr[j + 3];
    int a4 = csr[j + 4],  a5 = csr[j + 5],  a6 = csr[j + 6],  a7 = csr[j + 7];
    int a8 = csr[j + 8],  a9 = csr[j + 9],  aA = csr[j + 10], aB = csr[j + 11];
    int aC = csr[j + 12], aD = csr[j + 13], aE = csr[j + 14], aF = csr[j + 15];
    uint u0 = *(const uint*)(P8 + (size_t)a0 * 256 + 4 * lane);
    uint u1 = *(const uint*)(P8 + (size_t)a1 * 256 + 4 * lane);
    uint u2 = *(const uint*)(P8 + (size_t)a2 * 256 + 4 * lane);
    uint u3 = *(const uint*)(P8 + (size_t)a3 * 256 + 4 * lane);
    uint u4 = *(const uint*)(P8 + (size_t)a4 * 256 + 4 * lane);
    uint u5 = *(const uint*)(P8 + (size_t)a5 * 256 + 4 * lane);
    uint u6 = *(const uint*)(P8 + (size_t)a6 * 256 + 4 * lane);
    uint u7 = *(const uint*)(P8 + (size_t)a7 * 256 + 4 * lane);
    uint v0 = *(const uint*)(P8 + (size_t)a8 * 256 + 4 * lane);
    uint v1 = *(const uint*)(P8 + (size_t)a9 * 256 + 4 * lane);
    uint v2 = *(const uint*)(P8 + (size_t)aA * 256 + 4 * lane);
    uint v3 = *(const uint*)(P8 + (size_t)aB * 256 + 4 * lane);
    uint v4 = *(const uint*)(P8 + (size_t)aC * 256 + 4 * lane);
    uint v5 = *(const uint*)(P8 + (size_t)aD * 256 + 4 * lane);
    uint v6 = *(const uint*)(P8 + (size_t)aE * 256 + 4 * lane);
    uint v7 = *(const uint*)(P8 + (size_t)aF * 256 + 4 * lane);
    s0 += dec8_0(u0) + dec8_0(u1) + dec8_0(u2) + dec8_0(u3);
    s1 += dec8_1(u0) + dec8_1(u1) + dec8_1(u2) + dec8_1(u3);
    s2 += dec8_2(u0) + dec8_2(u1) + dec8_2(u2) + dec8_2(u3);
    s3 += dec8_3(u0) + dec8_3(u1) + dec8_3(u2) + dec8_3(u3);
    t0 += dec8_0(u4) + dec8_0(u5) + dec8_0(u6) + dec8_0(u7);
    t1 += dec8_1(u4) + dec8_1(u5) + dec8_1(u6) + dec8_1(u7);
    t2 += dec8_2(u4) + dec8_2(u5) + dec8_2(u6) + dec8_2(u7);
    t3 += dec8_3(u4) + dec8_3(u5) + dec8_3(u6) + dec8_3(u7);
    s0 += dec8_0(v0) + dec8_0(v1) + dec8_0(v2) + dec8_0(v3);
    s1 += dec8_1(v0) + dec8_1(v1) + dec8_1(v2) + dec8_1(v3);
    s2 += dec8_2(v0) + dec8_2(v1) + dec8_2(v2) + dec8_2(v3);
    s3 += dec8_3(v0) + dec8_3(v1) + dec8_3(v2) + dec8_3(v3);
    t0 += dec8_0(v4) + dec8_0(v5) + dec8_0(v6) + dec8_0(v7);
    t1 += dec8_1(v4) + dec8_1(v5) + dec8_1(v6) + dec8_1(v7);
    t2 += dec8_2(v4) + dec8_2(v5) + dec8_2(v6) + dec8_2(v7);
    t3 += dec8_3(v4) + dec8_3(v5) + dec8_3(v6) + dec8_3(v7);
  }
  if (j + 8 <= e) {
    int a0 = csr[j],     a1 = csr[j + 1], a2 = csr[j + 2], a3 = csr[j + 3];
    int a4 = csr[j + 4], a5 = csr[j + 5], a6 = csr[j + 6], a7 = csr[j + 7];
    uint u0 = *(const uint*)(P8 + (size_t)a0 * 256 + 4 * lane);
    uint u1 = *(const uint*)(P8 + (size_t)a1 * 256 + 4 * lane);
    uint u2 = *(const uint*)(P8 + (size_t)a2 * 256 + 4 * lane);
    uint u3 = *(const uint*)(P8 + (size_t)a3 * 256 + 4 * lane);
    uint u4 = *(const uint*)(P8 + (size_t)a4 * 256 + 4 * lane);
    uint u5 = *(const uint*)(P8 + (size_t)a5 * 256 + 4 * lane);
    uint u6 = *(const uint*)(P8 + (size_t)a6 * 256 + 4 * lane);
    uint u7 = *(const uint*)(P8 + (size_t)a7 * 256 + 4 * lane);
    s0 += dec8_0(u0) + dec8_0(u1) + dec8_0(u2) + dec8_0(u3);
    s1 += dec8_1(u0) + dec8_1(u1) + dec8_1(u2) + dec8_1(u3);
    s2 += dec8_2(u0) + dec8_2(u1) + dec8_2(u2) + dec8_2(u3);
    s3 += dec8_3(u0) + dec8_3(u1) + dec8_3(u2) + dec8_3(u3);
    t0 += dec8_0(u4) + dec8_0(u5) + dec8_0(u6) + dec8_0(u7);
    t1 += dec8_1(u4) + dec8_1(u5) + dec8_1(u6) + dec8_1(u7);
    t2 += dec8_2(u4) + dec8_2(u5) + dec8_2(u6) + dec8_2(u7);
    t3 += dec8_3(u4) + dec8_3(u5) + dec8_3(u6) + dec8_3(u7);
    j += 8;
  }
  if (j + 4 <= e) {
    int a0 = csr[j], a1 = csr[j + 1], a2 = csr[j + 2], a3 = csr[j + 3];
    uint u0 = *(const uint*)(P8 + (size_t)a0 * 256 + 4 * lane);
    uint u1 = *(const uint*)(P8 + (size_t)a1 * 256 + 4 * lane);
    uint u2 = *(const uint*)(P8 + (size_t)a2 * 256 + 4 * lane);
    uint u3 = *(const uint*)(P8 + (size_t)a3 * 256 + 4 * lane);
    s0 += dec8_0(u0) + dec8_0(u1) + dec8_0(u2) + dec8_0(u3);
    s1 += dec8_1(u0) + dec8_1(u1) + dec8_1(u2) + dec8_1(u3);
    s2 += dec8_2(u0) + dec8_2(u1) + dec8_2(u2) + dec8_2(u3);
    s3 += dec8_3(u0) + dec8_3(u1) + dec8_3(u2) + dec8_3(u3);
    j += 4;
  }
  for (; j < e; ++j) {
    uint u0 = *(const uint*)(P8 + (size_t)csr[j] * 256 + 4 * lane);
    s0 += dec8_0(u0);
    s1 += dec8_1(u0);
    s2 += dec8_2(u0);
    s3 += dec8_3(u0);
  }
  s0 += t0; s1 += t1; s2 += t2; s3 += t3;
  // cross-half exchange: low lanes get delta sums, high lanes get clean sums
  float o0 = __shfl_xor(s0, 32, 64);
  float o1 = __shfl_xor(s1, 32, 64);
  float o2 = __shfl_xor(s2, 32, 64);
  float o3 = __shfl_xor(s3, 32, 64);
  bool hi = lane >= 32;                       // hi half -> noisy branch
  float m0 = hi ? (s0 + o0) : s0;             // noisy = clean + delta
  float m1 = hi ? (s1 + o1) : s1;
  float m2 = hi ? (s2 + o2) : s2;
  float m3 = hi ? (s3 + o3) : s3;
  float invd = 1.f / (float)max(e - b, 1);
  // Rb row [2][128] bf16: element offset 4*lane spans clean(0-31)/noisy(32-63)
  uint2 rp = *(const uint2*)(Rb + (size_t)node * 256 + 4 * lane);
  float rvx = b2f_lo(rp.x), rvy = b2f_hi(rp.x);
  float rvz = b2f_lo(rp.y), rvw = b2f_hi(rp.y);
  float4 bb = *(const float4*)(bias + 4 * lq);
  float q0 = fmaxf(m0 * invd + bb.x + rvx, 0.f);
  float q1 = fmaxf(m1 * invd + bb.y + rvy, 0.f);
  float q2 = fmaxf(m2 * invd + bb.z + rvz, 0.f);
  float q3 = fmaxf(m3 * invd + bb.w + rvw, 0.f);
  size_t arow = (size_t)(2 * node + (hi ? 1 : 0)) * 128 + 4 * lq;
  ushort4 pk;
  pk.x = f2b(q0); pk.y = f2b(q1); pk.z = f2b(q2); pk.w = f2b(q3);
  *(ushort4*)(bout + arow) = pk;
  if (WF32) {
    float* dst = (hi ? f1 : f0) + (size_t)node * 128 + 4 * lq;
    *(float4*)dst = make_float4(q0, q1, q2, q3);
  }
}

// layer 2: pair-split gather (round-11 form, kept: neutral but fewer insts).
// Per edge pair (2k, 2k+1): lo half-wave handles edge 2k, hi half edge 2k+1.
// Each lane reads the pair's clean row as uint (2 bf16 cols) and the delta
// row as ushort (2 fp8 cols). Sums recombined via shfl_xor(32), redistributed
// col=lane via shfl(lane>>1). Fused log_softmax per branch over 47 lanes.
__global__ __launch_bounds__(256) void agg47_dual(
    const ushort* __restrict__ Pzc, const uchar* __restrict__ Pzd,
    const float* __restrict__ Rz, const float* __restrict__ bias,
    const int* __restrict__ off, const int* __restrict__ csr,
    float* __restrict__ z0, float* __restrict__ z1, float* __restrict__ y0,
    float* __restrict__ y1, int N) {
  int node = (blockIdx.x * blockDim.x + threadIdx.x) >> 6;
  int lane = threadIdx.x & 63;
  if (node >= N) return;
  int lq = lane & 31;
  bool hiH = lane >= 32;
  int b = off[node], e = off[node + 1];
  float c0s = 0.f, c1s = 0.f;   // clean partial sums, cols 2lq / 2lq+1
  float c2s = 0.f, c3s = 0.f;   // second accumulator pair (ILP)
  float g0 = 0.f, g1 = 0.f;     // delta partial sums, cols 2lq / 2lq+1
  float h0 = 0.f, h1 = 0.f;
  int j = b;
  for (; j + 16 <= e; j += 16) {
    int a0 = csr[j],      a1 = csr[j + 1],  a2 = csr[j + 2],  a3 = csr[j + 3];
    int a4 = csr[j + 4],  a5 = csr[j + 5],  a6 = csr[j + 6],  a7 = csr[j + 7];
    int a8 = csr[j + 8],  a9 = csr[j + 9],  aA = csr[j + 10], aB = csr[j + 11];
    int aC = csr[j + 12], aD = csr[j + 13], aE = csr[j + 14], aF = csr[j + 15];
    int p0 = hiH ? a1 : a0;   // pair split: lo half even edge, hi half odd
    int p1 = hiH ? a3 : a2;
    int p2 = hiH ? a5 : a4;
    int p3 = hiH ? a7 : a6;
    int p4 = hiH ? a9 : a8;
    int p5 = hiH ? aB : aA;
    int p6 = hiH ? aD : aC;
    int p7 = hiH ? aF : aE;
    uint c0 = *(const uint*)(Pzc + (size_t)p0 * 64 + 2 * lq);
    uint c1 = *(const uint*)(Pzc + (size_t)p1 * 64 + 2 * lq);
    uint c2 = *(const uint*)(Pzc + (size_t)p2 * 64 + 2 * lq);
    uint c3 = *(const uint*)(Pzc + (size_t)p3 * 64 + 2 * lq);
    uint c4 = *(const uint*)(Pzc + (size_t)p4 * 64 + 2 * lq);
    uint c5 = *(const uint*)(Pzc + (size_t)p5 * 64 + 2 * lq);
    uint c6 = *(const uint*)(Pzc + (size_t)p6 * 64 + 2 * lq);
    uint c7 = *(const uint*)(Pzc + (size_t)p7 * 64 + 2 * lq);
    uint d0 = *(const ushort*)(Pzd + (size_t)p0 * 64 + 2 * lq);
    uint d1 = *(const ushort*)(Pzd + (size_t)p1 * 64 + 2 * lq);
    uint d2 = *(const ushort*)(Pzd + (size_t)p2 * 64 + 2 * lq);
    uint d3 = *(const ushort*)(Pzd + (size_t)p3 * 64 + 2 * lq);
    uint d4 = *(const ushort*)(Pzd + (size_t)p4 * 64 + 2 * lq);
    uint d5 = *(const ushort*)(Pzd + (size_t)p5 * 64 + 2 * lq);
    uint d6 = *(const ushort*)(Pzd + (size_t)p6 * 64 + 2 * lq);
    uint d7 = *(const ushort*)(Pzd + (size_t)p7 * 64 + 2 * lq);
    c0s += b2f_lo(c0) + b2f_lo(c1) + b2f_lo(c2) + b2f_lo(c3);
    c1s += b2f_hi(c0) + b2f_hi(c1) + b2f_hi(c2) + b2f_hi(c3);
    c2s += b2f_lo(c4) + b2f_lo(c5) + b2f_lo(c6) + b2f_lo(c7);
    c3s += b2f_hi(c4) + b2f_hi(c5) + b2f_hi(c6) + b2f_hi(c7);
    g0 += dec8_0(d0) + dec8_0(d1) + dec8_0(d2) + dec8_0(d3);
    g1 += dec8_1(d0) + dec8_1(d1) + dec8_1(d2) + dec8_1(d3);
    h0 += dec8_0(d4) + dec8_0(d5) + dec8_0(d6) + dec8_0(d7);
    h1 += dec8_1(d4) + dec8_1(d5) + dec8_1(d6) + dec8_1(d7);
  }
  if (j + 8 <= e) {
    int a0 = csr[j],     a1 = csr[j + 1], a2 = csr[j + 2], a3 = csr[j + 3];
    int a4 = csr[j + 4], a5 = csr[j + 5], a6 = csr[j + 6], a7 = csr[j + 7];
    int p0 = hiH ? a1 : a0;
    int p1 = hiH ? a3 : a2;
    int p2 = hiH ? a5 : a4;
    int p3 = hiH ? a7 : a6;
    uint c0 = *(const uint*)(Pzc + (size_t)p0 * 64 + 2 * lq);
    uint c1 = *(const uint*)(Pzc + (size_t)p1 * 64 + 2 * lq);
    uint c2 = *(const uint*)(Pzc + (size_t)p2 * 64 + 2 * lq);
    uint c3 = *(const uint*)(Pzc + (size_t)p3 * 64 + 2 * lq);
    uint d0 = *(const ushort*)(Pzd + (size_t)p0 * 64 + 2 * lq);
    uint d1 = *(const ushort*)(Pzd + (size_t)p1 * 64 + 2 * lq);
    uint d2 = *(const ushort*)(Pzd + (size_t)p2 * 64 + 2 * lq);
    uint d3 = *(const ushort*)(Pzd + (size_t)p3 * 64 + 2 * lq);
    c0s += b2f_lo(c0) + b2f_lo(c1) + b2f_lo(c2) + b2f_lo(c3);
    c1s += b2f_hi(c0) + b2f_hi(c1) + b2f_hi(c2) + b2f_hi(c3);
    g0 += dec8_0(d0) + dec8_0(d1) + dec8_0(d2) + dec8_0(d3);
    g1 += dec8_1(d0) + dec8_1(d1) + dec8_1(d2) + dec8_1(d3);
    j += 8;
  }
  if (j + 4 <= e) {
    int a0 = csr[j], a1 = csr[j + 1], a2 = csr[j + 2], a3 = csr[j + 3];
    int p0 = hiH ? a1 : a0;
    int p1 = hiH ? a3 : a2;
    uint c0 = *(const uint*)(Pzc + (size_t)p0 * 64 + 2 * lq);
    uint c1 = *(const uint*)(Pzc + (size_t)p1 * 64 + 2 * lq);
    uint d0 = *(const ushort*)(Pzd + (size_t)p0 * 64 + 2 * lq);
    uint d1 = *(const ushort*)(Pzd + (size_t)p1 * 64 + 2 * lq);
    c0s += b2f_lo(c0) + b2f_lo(c1);
    c1s += b2f_hi(c0) + b2f_hi(c1);
    g0 += dec8_0(d0) + dec8_0(d1);
    g1 += dec8_1(d0) + dec8_1(d1);
    j += 4;
  }
  if (j + 2 <= e) {
    int a0 = csr[j], a1 = csr[j + 1];
    int p0 = hiH ? a1 : a0;
    uint c0 = *(const uint*)(Pzc + (size_t)p0 * 64 + 2 * lq);
    uint d0 = *(const ushort*)(Pzd + (size_t)p0 * 64 + 2 * lq);
    c0s += b2f_lo(c0);
    c1s += b2f_hi(c0);
    g0 += dec8_0(d0);
    g1 += dec8_1(d0);
    j += 2;
  }
  if (j < e) {          // lone edge: only lo half processes it
    int a0 = csr[j];
    if (!hiH) {
      uint c0 = *(const uint*)(Pzc + (size_t)a0 * 64 + 2 * lq);
      uint d0 = *(const ushort*)(Pzd + (size_t)a0 * 64 + 2 * lq);
      c0s += b2f_lo(c0);
      c1s += b2f_hi(c0);
      g0 += dec8_0(d0);
      g1 += dec8_1(d0);
    }
  }
  c0s += c2s; c1s += c3s; g0 += h0; g1 += h1;
  // combine the two halves' edge subsets -> totals on all lanes
  c0s += __shfl_xor(c0s, 32, 64);
  c1s += __shfl_xor(c1s, 32, 64);
  g0 += __shfl_xor(g0, 32, 64);
  g1 += __shfl_xor(g1, 32, 64);
  // value for col = lane lives on lane>>1 (component lane&1)
  float cc0 = __shfl(c0s, lane >> 1, 64);
  float cc1 = __shfl(c1s, lane >> 1, 64);
  float dd0 = __shfl(g0, lane >> 1, 64);
  float dd1 = __shfl(g1, lane >> 1, 64);
  float cl = (lane & 1) ? cc1 : cc0;
  float dl = (lane & 1) ? dd1 : dd0;
  bool v = lane < 47;
  float invd = 1.f / (float)max(e - b, 1);
  float rc = Rz[(size_t)node * 96 + lane];        // lanes 47..63: pad/garbage
  float rn = Rz[(size_t)node * 96 + 48 + lane];   // (masked by v below)
  float bl = v ? bias[lane] : 0.f;
  float za = v ? (cl * invd + bl + rc) : -INFINITY;
  float zn = v ? ((cl + dl) * invd + bl + rn) : -INFINITY;
  float ma = za, mb = zn;
#pragma unroll
  for (int d = 1; d < 64; d <<= 1) {
    ma = fmaxf(ma, __shfl_xor(ma, d, 64));
    mb = fmaxf(mb, __shfl_xor(mb, d, 64));
  }
  float sa = v ? __expf(za - ma) : 0.f;
  float sb = v ? __expf(zn - mb) : 0.f;
#pragma unroll
  for (int d = 1; d < 64; d <<= 1) {
    sa += __shfl_xor(sa, d, 64);
    sb += __shfl_xor(sb, d, 64);
  }
  float lsa = logf(sa) + ma;
  float lsb = logf(sb) + mb;
  if (v) {
    z0[(size_t)node * 47 + lane] = za;
    y0[(size_t)node * 47 + lane] = za - lsa;
    z1[(size_t)node * 47 + lane] = zn;
    y1[(size_t)node * 47 + lane] = zn - lsb;
  }
}

// ---------------------------------------------------------------------------
extern "C" void kernel_launch(void* const* d_in, const int* in_sizes, int n_in,
                              void* d_out, int out_size, void* d_ws,
                              size_t ws_size, hipStream_t stream) {
  const float* x = (const float*)d_in[0];
  const int* ei = (const int*)d_in[1];
  const float* noise = (const float*)d_in[2];
  const float* Wl0 = (const float*)d_in[3];
  const float* bl0 = (const float*)d_in[4];
  const float* Wr0 = (const float*)d_in[5];
  const float* Wl1 = (const float*)d_in[6];
  const float* bl1 = (const float*)d_in[7];
  const float* Wr1 = (const float*)d_in[8];
  const float* Wl2 = (const float*)d_in[9];
  const float* bl2 = (const float*)d_in[10];
  const float* Wr2 = (const float*)d_in[11];

  const int N = in_sizes[0] / 128;
  const int E = in_sizes[1] / 2;
  const int M = 2 * N;

  float* out = (float*)d_out;
  float* h_p = out;
  float* y_p = h_p + (size_t)N * 128;
  float* z_p = y_p + (size_t)N * 47;
  float* h_n = z_p + (size_t)N * 47;
  float* y_n = h_n + (size_t)N * 128;
  float* z_n = y_n + (size_t)N * 47;

  char* w = (char*)d_ws;
  auto alloc = [&](size_t bytes) {
    void* p = (void*)w;
    w += (bytes + 511) & ~(size_t)511;
    return p;
  };
  ushort* XB = (ushort*)alloc((size_t)M * 128 * 2);   // bf16 [M][128] interleaved
  uchar* P8 = (uchar*)alloc((size_t)N * 256);         // fp8 clean|delta rows
  ushort* Rb = (ushort*)alloc((size_t)M * 128 * 2);   // bf16 self-term L0/L1
  float* Rz = (float*)alloc((size_t)N * 128 * 4);     // f32 self-term L2 (96 used)
  ushort* WB0 = (ushort*)alloc(256 * 128 * 2);
  ushort* WB1 = (ushort*)alloc(256 * 128 * 2);
  ushort* WB2 = (ushort*)alloc(94 * 128 * 2);
  int* cnt = (int*)alloc((size_t)N * 4);
  int* off = (int*)alloc((size_t)(N + 1) * 4);
  int* rank = (int*)alloc((size_t)E * 4);
  int* loc = (int*)alloc((size_t)N * 4);
  int* bsum = (int*)alloc((size_t)256 * 4);
  int* csr = (int*)alloc((size_t)E * 4);
  // layer-2 tables carved from P8 region (N*128 B + N*64 B <= N*256 B)
  ushort* Pzc = (ushort*)P8;
  uchar* Pzd = P8 + (size_t)N * 128;

  int nwb = (N + 3) / 4;       // 1 wave/node
  int rb = (M + 127) / 128;    // GEMM row blocks
  int eb = (E + 255) / 256;    // count blocks (merged into prep; eb <= nwb)
  int fb = (E + 1023) / 1024;  // fill blocks (merged into gemm0; 2 edges/thr)
  int sb = (N + 1023) / 1024;

  // cnt = 0 (200 KB, ~2 us) must precede the count atomics inside prep
  hipMemsetAsync(cnt, 0, (size_t)N * 4, stream);

  // prep: noisy+bf16 convert, weight convert, CSR count (one dispatch)
  prep_kernel<<<nwb, 256, 0, stream>>>(x, noise, XB, Wl0, Wr0, Wl1, Wr1, Wl2,
                                       Wr2, WB0, WB1, WB2, ei + E, cnt, rank,
                                       E, eb, N);

  scan_blocks<<<sb, 256, 0, stream>>>(cnt, loc, bsum, N);
  scan_apply<<<(N + 255) / 256, 256, 0, stream>>>(loc, bsum, off, N, E, sb);

  // layer 0 (+ CSR fill scatter in extra blocks)
  gemm_fused<<<rb + fb, 512, 0, stream>>>(XB, WB0, P8, Rb, M, ei, ei + E,
                                          rank, off, csr, E, rb);
  agg_dual128<false><<<nwb, 256, 0, stream>>>(P8, Rb, bl0, off, csr, nullptr,
                                              nullptr, XB, N);
  // layer 1 (h outputs + bf16 for next layer); no fill blocks
  gemm_fused<<<rb, 512, 0, stream>>>(XB, WB1, P8, Rb, M, ei, ei + E, rank,
                                     off, csr, E, rb);
  agg_dual128<true><<<nwb, 256, 0, stream>>>(P8, Rb, bl1, off, csr, h_p, h_n,
                                             XB, N);
  // layer 2 + fused log_softmax
  gemm_l2<<<rb, 256, 0, stream>>>(XB, WB2, Pzc, Pzd, Rz, M);
  agg47_dual<<<nwb, 256, 0, stream>>>(Pzc, Pzd, Rz, bl2, off, csr, z_p, z_n,
                                      y_p, y_n, N);
}